// Round 4
// baseline (504.473 us; speedup 1.0000x reference)
//
#include <hip/hip_runtime.h>

#define NN 100000
#define NE 1600000
#define NG 64
#define DI 128
#define DH 256
#define DO 128

using short8 = __attribute__((ext_vector_type(8))) short;
using f32x4  = __attribute__((ext_vector_type(4))) float;

__device__ __forceinline__ float bf2f(unsigned short u) {
    return __uint_as_float(((unsigned)u) << 16);
}
__device__ __forceinline__ unsigned short f2bf(float f) {
    unsigned u = __float_as_uint(f);
    unsigned r = (u + 0x7FFFu + ((u >> 16) & 1u)) >> 16;   // RNE
    return (unsigned short)r;
}

// ---------------- small utility kernels ----------------

__global__ void k_zero(float* p, int n) {
    int i = blockIdx.x * blockDim.x + threadIdx.x;
    if (i < n) p[i] = 0.0f;
}
__global__ void k_zero_int(int* p, int n) {
    int i = blockIdx.x * blockDim.x + threadIdx.x;
    if (i < n) p[i] = 0;
}
__global__ void k_hist(const int* __restrict__ dst, int* __restrict__ cnt, int e) {
    int i = blockIdx.x * blockDim.x + threadIdx.x;
    if (i < e) atomicAdd(&cnt[dst[i]], 1);
}
__global__ void k_dinv(const int* __restrict__ cnt_in, float* __restrict__ dinv, int n) {
    int i = blockIdx.x * blockDim.x + threadIdx.x;
    if (i < n) dinv[i] = rsqrtf((float)(cnt_in[i] + 1));
}
__global__ void k_copy_int(const int* __restrict__ a, int* __restrict__ b, int n) {
    int i = blockIdx.x * blockDim.x + threadIdx.x;
    if (i < n) b[i] = a[i];
}

// f32 -> bf16 bulk convert (4 elems/thread)
__global__ void k_cvt_bf(const float* __restrict__ in, unsigned short* __restrict__ out, int n4) {
    int i = blockIdx.x * blockDim.x + threadIdx.x;
    if (i >= n4) return;
    float4 v = ((const float4*)in)[i];
    ushort4 o;
    o.x = f2bf(v.x); o.y = f2bf(v.y); o.z = f2bf(v.z); o.w = f2bf(v.w);
    ((ushort4*)out)[i] = o;
}

// W (KxN f32, row-major) -> Wt (NxK bf16)
__global__ void k_wt(const float* __restrict__ W, unsigned short* __restrict__ Wt, int K, int N) {
    int i = blockIdx.x * blockDim.x + threadIdx.x;
    if (i >= K * N) return;
    int k = i / N, n = i % N;
    Wt[n * K + k] = f2bf(W[i]);
}

// ---------------- exclusive scan (2-level) ----------------

__global__ void k_scan1(const int* __restrict__ in, int* __restrict__ out,
                        int* __restrict__ bsum, int n) {
    __shared__ int sh[256];
    int t = threadIdx.x;
    int i = blockIdx.x * 256 + t;
    int v = (i < n) ? in[i] : 0;
    sh[t] = v;
    __syncthreads();
    for (int off = 1; off < 256; off <<= 1) {
        int add = (t >= off) ? sh[t - off] : 0;
        __syncthreads();
        sh[t] += add;
        __syncthreads();
    }
    if (i < n) out[i] = sh[t] - v;
    if (t == 255) bsum[blockIdx.x] = sh[255];
}
__global__ void k_scan2(int* __restrict__ bsum, int nb) {
    __shared__ int sh[512];
    int t = threadIdx.x;
    int v = (t < nb) ? bsum[t] : 0;
    sh[t] = v;
    __syncthreads();
    for (int off = 1; off < 512; off <<= 1) {
        int add = (t >= off) ? sh[t - off] : 0;
        __syncthreads();
        sh[t] += add;
        __syncthreads();
    }
    if (t < nb) bsum[t] = sh[t] - v;
}
__global__ void k_scan3(int* __restrict__ out, const int* __restrict__ bsum,
                        int n, int total) {
    int i = blockIdx.x * 256 + threadIdx.x;
    if (i < n) out[i] += bsum[blockIdx.x];
    if (i == 0) out[n] = total;
}

// ---------------- CSR fill: dst-range pass for write locality ----------------

__global__ void k_fill_csr(const int* __restrict__ src, const int* __restrict__ dst,
                           int* __restrict__ cursor, int* __restrict__ csr_src,
                           int e, int lo, int hi) {
    int i = blockIdx.x * blockDim.x + threadIdx.x;
    if (i < e) {
        int d = dst[i];
        if (d >= lo && d < hi) {
            int pos = atomicAdd(&cursor[d], 1);
            csr_src[pos] = src[i];
        }
    }
}

// ---------------- layer-1 aggregation: out = A_hat @ feat (bf16->bf16), D=128 ----------------
// 16 lanes per node, short8 (16B) per lane.
__global__ __launch_bounds__(256) void k_agg16(const unsigned short* __restrict__ feat,
        const int* __restrict__ csr_src, const int* __restrict__ row_start,
        const float* __restrict__ dinv, unsigned short* __restrict__ out, int n) {
    int gid = blockIdx.x * blockDim.x + threadIdx.x;
    int node = gid >> 4;
    int lane = threadIdx.x & 15;
    if (node >= n) return;
    const short8* f8 = (const short8*)feat;
    float wd = dinv[node];
    short8 a = f8[(size_t)node * 16 + lane];
    float acc[8];
#pragma unroll
    for (int i = 0; i < 8; ++i) acc[i] = bf2f((unsigned short)a[i]) * wd;
    int j = row_start[node], end = row_start[node + 1];
    for (; j + 1 < end; j += 2) {
        int s0 = csr_src[j], s1 = csr_src[j + 1];
        float w0 = dinv[s0], w1 = dinv[s1];
        short8 v0 = f8[(size_t)s0 * 16 + lane];
        short8 v1 = f8[(size_t)s1 * 16 + lane];
#pragma unroll
        for (int i = 0; i < 8; ++i)
            acc[i] += w0 * bf2f((unsigned short)v0[i]) + w1 * bf2f((unsigned short)v1[i]);
    }
    if (j < end) {
        int s = csr_src[j];
        float w = dinv[s];
        short8 v = f8[(size_t)s * 16 + lane];
#pragma unroll
        for (int i = 0; i < 8; ++i) acc[i] += w * bf2f((unsigned short)v[i]);
    }
    short8 o;
#pragma unroll
    for (int i = 0; i < 8; ++i) o[i] = (short)f2bf(acc[i] * wd);
    ((short8*)out)[(size_t)node * 16 + lane] = o;
}

// ---------------- fused layer-2 aggregation + global_add_pool ----------------
// 32-lane groups, 16 consecutive nodes per group (batch sorted).
// pool partial in registers; atomic flush at graph boundary / group end.
__global__ __launch_bounds__(256) void k_agg_pool(const unsigned short* __restrict__ feat,
        const int* __restrict__ csr_src, const int* __restrict__ row_start,
        const float* __restrict__ dinv, const int* __restrict__ batch,
        float* __restrict__ out, float* __restrict__ cnt, int n) {
    const int R = 16;
    int group = blockIdx.x * 8 + (threadIdx.x >> 5);
    int lane = threadIdx.x & 31;
    int start = group * R;
    if (start >= n) return;
    int end = min(start + R, n);
    const ushort4* f4 = (const ushort4*)feat;

    float4 pacc = make_float4(0.f, 0.f, 0.f, 0.f);
    int curg = batch[start];
    int run = 0;

    for (int v = start; v < end; ++v) {
        int gv = batch[v];
        if (gv != curg) {
            float* o = out + curg * 128 + lane * 4;
            atomicAdd(o + 0, pacc.x); atomicAdd(o + 1, pacc.y);
            atomicAdd(o + 2, pacc.z); atomicAdd(o + 3, pacc.w);
            if (lane == 0) atomicAdd(&cnt[curg], (float)run);
            pacc = make_float4(0.f, 0.f, 0.f, 0.f);
            run = 0; curg = gv;
        }
        float wd = dinv[v];
        ushort4 a = f4[(size_t)v * 32 + lane];
        float4 acc;
        acc.x = bf2f(a.x) * wd; acc.y = bf2f(a.y) * wd;
        acc.z = bf2f(a.z) * wd; acc.w = bf2f(a.w) * wd;
        int j = row_start[v], e2 = row_start[v + 1];
        for (; j + 1 < e2; j += 2) {
            int s0 = csr_src[j], s1 = csr_src[j + 1];
            float w0 = dinv[s0], w1 = dinv[s1];
            ushort4 v0 = f4[(size_t)s0 * 32 + lane];
            ushort4 v1 = f4[(size_t)s1 * 32 + lane];
            acc.x += w0 * bf2f(v0.x) + w1 * bf2f(v1.x);
            acc.y += w0 * bf2f(v0.y) + w1 * bf2f(v1.y);
            acc.z += w0 * bf2f(v0.z) + w1 * bf2f(v1.z);
            acc.w += w0 * bf2f(v0.w) + w1 * bf2f(v1.w);
        }
        if (j < e2) {
            int s = csr_src[j];
            float w = dinv[s];
            ushort4 vv = f4[(size_t)s * 32 + lane];
            acc.x += w * bf2f(vv.x); acc.y += w * bf2f(vv.y);
            acc.z += w * bf2f(vv.z); acc.w += w * bf2f(vv.w);
        }
        pacc.x += acc.x * wd; pacc.y += acc.y * wd;
        pacc.z += acc.z * wd; pacc.w += acc.w * wd;
        run++;
    }
    float* o = out + curg * 128 + lane * 4;
    atomicAdd(o + 0, pacc.x); atomicAdd(o + 1, pacc.y);
    atomicAdd(o + 2, pacc.z); atomicAdd(o + 3, pacc.w);
    if (lane == 0) atomicAdd(&cnt[curg], (float)run);
}

// ---------------- bf16 MFMA GEMM: C = act(A @ Bt^T + bias), BM=128, 512 thr ----------------
template<int K, int N, bool RELU, bool BIAS>
__global__ __launch_bounds__(512) void k_gemm_bf(const unsigned short* __restrict__ A,
        const unsigned short* __restrict__ Bt, const float* __restrict__ bias,
        unsigned short* __restrict__ C, int M) {
    constexpr int BM = 128;
    __shared__ unsigned short As[BM * K];   // XOR-swizzled rows
    __shared__ unsigned short Bs[N * K];

    const int tid = threadIdx.x;
    const int bm = blockIdx.x * BM;

    constexpr int AC = BM * K / 8;
    for (int c = tid; c < AC; c += 512) {
        int row = c / (K / 8);
        int kc  = (c % (K / 8)) * 8;
        uint4 v = make_uint4(0, 0, 0, 0);
        int gr = bm + row;
        if (gr < M) v = *(const uint4*)(A + (size_t)gr * K + kc);
        int byte = row * (2 * K) + ((kc * 2) ^ ((row & 7) << 4));
        *(uint4*)((char*)As + byte) = v;
    }
    constexpr int BC = N * K / 8;
    for (int c = tid; c < BC; c += 512) {
        int col = c / (K / 8);
        int kc  = (c % (K / 8)) * 8;
        uint4 v = *(const uint4*)(Bt + (size_t)col * K + kc);
        int byte = col * (2 * K) + ((kc * 2) ^ ((col & 7) << 4));
        *(uint4*)((char*)Bs + byte) = v;
    }
    __syncthreads();

    const int w  = tid >> 6;
    const int l  = tid & 63;
    const int lr = l & 15;
    const int lg = l >> 4;
    const int r0 = w * 16;

    constexpr int NT = N / 16;
    f32x4 acc[NT] = {};

    const int arow  = r0 + lr;
    const int abase = arow * (2 * K);
    const int aswz  = (arow & 7) << 4;

#pragma unroll
    for (int ks = 0; ks < K / 32; ++ks) {
        int kb = ks * 64 + lg * 16;
        short8 a = *(const short8*)((const char*)As + abase + (kb ^ aswz));
#pragma unroll
        for (int n = 0; n < NT; ++n) {
            int col = n * 16 + lr;
            short8 b = *(const short8*)((const char*)Bs + col * (2 * K) + (kb ^ ((col & 7) << 4)));
            acc[n] = __builtin_amdgcn_mfma_f32_16x16x32_bf16(a, b, acc[n], 0, 0, 0);
        }
    }

#pragma unroll
    for (int n = 0; n < NT; ++n) {
        int col = n * 16 + lr;
        float bb = BIAS ? bias[col] : 0.0f;
#pragma unroll
        for (int r = 0; r < 4; ++r) {
            int row = bm + r0 + lg * 4 + r;
            if (row < M) {
                float v = acc[n][r] + bb;
                if (RELU) v = fmaxf(v, 0.f);
                C[(size_t)row * N + col] = f2bf(v);
            }
        }
    }
}

__global__ void k_biasfix(const float* __restrict__ bias, const float* __restrict__ cnt,
                          float* __restrict__ out) {
    int idx = blockIdx.x * blockDim.x + threadIdx.x;
    if (idx >= NG * 128) return;
    int g = idx >> 7, c = idx & 127;
    out[idx] += bias[c] * cnt[g];
}

// ---------------- launch ----------------

extern "C" void kernel_launch(void* const* d_in, const int* in_sizes, int n_in,
                              void* d_out, int out_size, void* d_ws, size_t ws_size,
                              hipStream_t stream) {
    const float* x     = (const float*)d_in[0];
    const int*   ei    = (const int*)d_in[1];
    const int*   batch = (const int*)d_in[2];
    const float* W1    = (const float*)d_in[3];
    const float* b1    = (const float*)d_in[4];
    const float* W2    = (const float*)d_in[5];
    const float* b2    = (const float*)d_in[6];
    float* out = (float*)d_out;

    const int* src = ei;
    const int* dst = ei + NE;

    char* ws = (char*)d_ws;
    float*          dinv   = (float*)(ws + 0);
    int*            cnt_in = (int*)(ws + 524288);
    int*            rowst  = (int*)(ws + 1048576);
    int*            bsum   = (int*)(ws + 1572864);
    float*          cnt    = (float*)(ws + 1576960);
    unsigned short* w1t    = (unsigned short*)(ws + 1581056);   // 256x128 bf16
    unsigned short* w2t    = (unsigned short*)(ws + 1646592);   // 128x256 bf16
    int*            csr    = (int*)(ws + 1712128);              // 6.4 MB
    unsigned short* xbf    = (unsigned short*)(ws + 8388608);   // 25.6 MB
    unsigned short* agg1   = (unsigned short*)(ws + 33988608);  // 25.6 MB
    unsigned short* h1     = (unsigned short*)(ws + 59588608);  // 51.2 MB
    unsigned short* tbf    = (unsigned short*)(ws + 110788608); // 25.6 MB

    const int BLK = 256;
    auto cdiv = [](int a, int b) { return (a + b - 1) / b; };
    const int NB = cdiv(NN, 256);

    // ---- conversions ----
    k_cvt_bf<<<cdiv(NN * 32, BLK), BLK, 0, stream>>>(x, xbf, NN * 32);
    k_wt<<<cdiv(DI * DH, BLK), BLK, 0, stream>>>(W1, w1t, DI, DH);
    k_wt<<<cdiv(DH * DO, BLK), BLK, 0, stream>>>(W2, w2t, DH, DO);

    // ---- degree + CSR build ----
    k_zero_int<<<cdiv(NN, BLK), BLK, 0, stream>>>(cnt_in, NN);
    k_hist<<<cdiv(NE, BLK), BLK, 0, stream>>>(dst, cnt_in, NE);
    k_scan1<<<NB, 256, 0, stream>>>(cnt_in, rowst, bsum, NN);
    k_scan2<<<1, 512, 0, stream>>>(bsum, NB);
    k_scan3<<<NB, 256, 0, stream>>>(rowst, bsum, NN, NE);
    k_dinv<<<cdiv(NN, BLK), BLK, 0, stream>>>(cnt_in, dinv, NN);
    k_copy_int<<<cdiv(NN, BLK), BLK, 0, stream>>>(rowst, cnt_in, NN);
    {
        const int NPASS = 4, NPP = (NN + NPASS - 1) / NPASS;
        for (int p = 0; p < NPASS; ++p)
            k_fill_csr<<<cdiv(NE, BLK), BLK, 0, stream>>>(src, dst, cnt_in, csr, NE,
                                                          p * NPP, (p + 1) * NPP);
    }

    // ---- layer 1 ----
    k_agg16<<<cdiv(NN * 16, BLK), BLK, 0, stream>>>(xbf, csr, rowst, dinv, agg1, NN);
    k_gemm_bf<DI, DH, true, true><<<cdiv(NN, 128), 512, 0, stream>>>(agg1, w1t, b1, h1, NN);

    // ---- layer 2 ----
    k_gemm_bf<DH, DO, false, false><<<cdiv(NN, 128), 512, 0, stream>>>(h1, w2t, nullptr, tbf, NN);

    // ---- fused agg2 + pool ----
    k_zero<<<cdiv(NG * 128, BLK), BLK, 0, stream>>>(out, NG * 128);
    k_zero<<<1, 64, 0, stream>>>(cnt, NG);
    k_agg_pool<<<cdiv(NN, 128), 256, 0, stream>>>(tbf, csr, rowst, dinv, batch, out, cnt, NN);
    k_biasfix<<<cdiv(NG * 128, BLK), BLK, 0, stream>>>(b2, cnt, out);
}

// Round 5
// 491.928 us; speedup vs baseline: 1.0255x; 1.0255x over previous
//
#include <hip/hip_runtime.h>

#define NN 100000
#define NE 1600000
#define NG 64
#define DI 128
#define DH 256
#define DO 128

using short8 = __attribute__((ext_vector_type(8))) short;
using f32x4  = __attribute__((ext_vector_type(4))) float;

__device__ __forceinline__ float bf2f(unsigned short u) {
    return __uint_as_float(((unsigned)u) << 16);
}
__device__ __forceinline__ unsigned short f2bf(float f) {
    unsigned u = __float_as_uint(f);
    unsigned r = (u + 0x7FFFu + ((u >> 16) & 1u)) >> 16;   // RNE
    return (unsigned short)r;
}

// ---------------- small utility kernels ----------------

__global__ void k_zero(float* p, int n) {
    int i = blockIdx.x * blockDim.x + threadIdx.x;
    if (i < n) p[i] = 0.0f;
}
__global__ void k_zero_int(int* p, int n) {
    int i = blockIdx.x * blockDim.x + threadIdx.x;
    if (i < n) p[i] = 0;
}
__global__ void k_hist(const int* __restrict__ dst, int* __restrict__ cnt, int e) {
    int i = blockIdx.x * blockDim.x + threadIdx.x;
    if (i < e) atomicAdd(&cnt[dst[i]], 1);
}

// f32 -> bf16 bulk convert (4 elems/thread)
__global__ void k_cvt_bf(const float* __restrict__ in, unsigned short* __restrict__ out, int n4) {
    int i = blockIdx.x * blockDim.x + threadIdx.x;
    if (i >= n4) return;
    float4 v = ((const float4*)in)[i];
    ushort4 o;
    o.x = f2bf(v.x); o.y = f2bf(v.y); o.z = f2bf(v.z); o.w = f2bf(v.w);
    ((ushort4*)out)[i] = o;
}

// W (KxN f32, row-major) -> Wt (NxK bf16)
__global__ void k_wt(const float* __restrict__ W, unsigned short* __restrict__ Wt, int K, int N) {
    int i = blockIdx.x * blockDim.x + threadIdx.x;
    if (i >= K * N) return;
    int k = i / N, n = i % N;
    Wt[n * K + k] = f2bf(W[i]);
}

// ---------------- exclusive scan (2-level) ----------------

__global__ void k_scan1(const int* __restrict__ in, int* __restrict__ out,
                        int* __restrict__ bsum, int n) {
    __shared__ int sh[256];
    int t = threadIdx.x;
    int i = blockIdx.x * 256 + t;
    int v = (i < n) ? in[i] : 0;
    sh[t] = v;
    __syncthreads();
    for (int off = 1; off < 256; off <<= 1) {
        int add = (t >= off) ? sh[t - off] : 0;
        __syncthreads();
        sh[t] += add;
        __syncthreads();
    }
    if (i < n) out[i] = sh[t] - v;
    if (t == 255) bsum[blockIdx.x] = sh[255];
}
__global__ void k_scan2(int* __restrict__ bsum, int nb) {
    __shared__ int sh[512];
    int t = threadIdx.x;
    int v = (t < nb) ? bsum[t] : 0;
    sh[t] = v;
    __syncthreads();
    for (int off = 1; off < 512; off <<= 1) {
        int add = (t >= off) ? sh[t - off] : 0;
        __syncthreads();
        sh[t] += add;
        __syncthreads();
    }
    if (t < nb) bsum[t] = sh[t] - v;
}
// finalize rowst, init cursor, compute dinv — fused epilogue
__global__ void k_scan3(int* __restrict__ rowst, const int* __restrict__ bsum,
                        int* __restrict__ cursor_deg, float* __restrict__ dinv,
                        int n, int total) {
    int i = blockIdx.x * 256 + threadIdx.x;
    if (i < n) {
        int deg = cursor_deg[i];
        dinv[i] = rsqrtf((float)(deg + 1));
        int rv = rowst[i] + bsum[blockIdx.x];
        rowst[i] = rv;
        cursor_deg[i] = rv;   // becomes fill cursor
    }
    if (i == 0) rowst[n] = total;
}

// ---------------- CSR fill: dst-range pass for write locality ----------------

__global__ void k_fill_csr(const int* __restrict__ src, const int* __restrict__ dst,
                           int* __restrict__ cursor, int* __restrict__ csr_src,
                           int e, int lo, int hi) {
    int i = blockIdx.x * blockDim.x + threadIdx.x;
    if (i < e) {
        int d = dst[i];
        if (d >= lo && d < hi) {
            int pos = atomicAdd(&cursor[d], 1);
            csr_src[pos] = src[i];
        }
    }
}

// ---------------- layer-1 aggregation: out = A_hat @ feat (bf16->bf16), D=128 ----------------
// 16 lanes per node, short8 (16B) per lane, 4-way neighbor unroll.
__global__ __launch_bounds__(256) void k_agg16(const unsigned short* __restrict__ feat,
        const int* __restrict__ csr_src, const int* __restrict__ row_start,
        const float* __restrict__ dinv, unsigned short* __restrict__ out, int n) {
    int gid = blockIdx.x * blockDim.x + threadIdx.x;
    int node = gid >> 4;
    int lane = threadIdx.x & 15;
    if (node >= n) return;
    const short8* f8 = (const short8*)feat;
    float wd = dinv[node];
    short8 a = f8[(size_t)node * 16 + lane];
    float acc[8];
#pragma unroll
    for (int i = 0; i < 8; ++i) acc[i] = bf2f((unsigned short)a[i]) * wd;
    int j = row_start[node], end = row_start[node + 1];
    for (; j + 3 < end; j += 4) {
        int s0 = csr_src[j], s1 = csr_src[j + 1], s2 = csr_src[j + 2], s3 = csr_src[j + 3];
        float w0 = dinv[s0], w1 = dinv[s1], w2 = dinv[s2], w3 = dinv[s3];
        short8 v0 = f8[(size_t)s0 * 16 + lane];
        short8 v1 = f8[(size_t)s1 * 16 + lane];
        short8 v2 = f8[(size_t)s2 * 16 + lane];
        short8 v3 = f8[(size_t)s3 * 16 + lane];
#pragma unroll
        for (int i = 0; i < 8; ++i)
            acc[i] += w0 * bf2f((unsigned short)v0[i]) + w1 * bf2f((unsigned short)v1[i])
                    + w2 * bf2f((unsigned short)v2[i]) + w3 * bf2f((unsigned short)v3[i]);
    }
    for (; j < end; ++j) {
        int s = csr_src[j];
        float w = dinv[s];
        short8 v = f8[(size_t)s * 16 + lane];
#pragma unroll
        for (int i = 0; i < 8; ++i) acc[i] += w * bf2f((unsigned short)v[i]);
    }
    short8 o;
#pragma unroll
    for (int i = 0; i < 8; ++i) o[i] = (short)f2bf(acc[i] * wd);
    ((short8*)out)[(size_t)node * 16 + lane] = o;
}

// ---------------- fused layer-2 aggregation + global_add_pool ----------------
// 32-lane groups, R=8 consecutive nodes per group (batch sorted), 4-way unroll.
__global__ __launch_bounds__(256) void k_agg_pool(const unsigned short* __restrict__ feat,
        const int* __restrict__ csr_src, const int* __restrict__ row_start,
        const float* __restrict__ dinv, const int* __restrict__ batch,
        float* __restrict__ out, float* __restrict__ cnt, int n) {
    const int R = 8;
    int group = blockIdx.x * 8 + (threadIdx.x >> 5);
    int lane = threadIdx.x & 31;
    int start = group * R;
    if (start >= n) return;
    int end = min(start + R, n);
    const ushort4* f4 = (const ushort4*)feat;

    float4 pacc = make_float4(0.f, 0.f, 0.f, 0.f);
    int curg = batch[start];
    int run = 0;

    for (int v = start; v < end; ++v) {
        int gv = batch[v];
        if (gv != curg) {
            float* o = out + curg * 128 + lane * 4;
            atomicAdd(o + 0, pacc.x); atomicAdd(o + 1, pacc.y);
            atomicAdd(o + 2, pacc.z); atomicAdd(o + 3, pacc.w);
            if (lane == 0) atomicAdd(&cnt[curg], (float)run);
            pacc = make_float4(0.f, 0.f, 0.f, 0.f);
            run = 0; curg = gv;
        }
        float wd = dinv[v];
        ushort4 a = f4[(size_t)v * 32 + lane];
        float4 acc;
        acc.x = bf2f(a.x) * wd; acc.y = bf2f(a.y) * wd;
        acc.z = bf2f(a.z) * wd; acc.w = bf2f(a.w) * wd;
        int j = row_start[v], e2 = row_start[v + 1];
        for (; j + 3 < e2; j += 4) {
            int s0 = csr_src[j], s1 = csr_src[j + 1], s2 = csr_src[j + 2], s3 = csr_src[j + 3];
            float w0 = dinv[s0], w1 = dinv[s1], w2 = dinv[s2], w3 = dinv[s3];
            ushort4 v0 = f4[(size_t)s0 * 32 + lane];
            ushort4 v1 = f4[(size_t)s1 * 32 + lane];
            ushort4 v2 = f4[(size_t)s2 * 32 + lane];
            ushort4 v3 = f4[(size_t)s3 * 32 + lane];
            acc.x += w0 * bf2f(v0.x) + w1 * bf2f(v1.x) + w2 * bf2f(v2.x) + w3 * bf2f(v3.x);
            acc.y += w0 * bf2f(v0.y) + w1 * bf2f(v1.y) + w2 * bf2f(v2.y) + w3 * bf2f(v3.y);
            acc.z += w0 * bf2f(v0.z) + w1 * bf2f(v1.z) + w2 * bf2f(v2.z) + w3 * bf2f(v3.z);
            acc.w += w0 * bf2f(v0.w) + w1 * bf2f(v1.w) + w2 * bf2f(v2.w) + w3 * bf2f(v3.w);
        }
        for (; j < e2; ++j) {
            int s = csr_src[j];
            float w = dinv[s];
            ushort4 vv = f4[(size_t)s * 32 + lane];
            acc.x += w * bf2f(vv.x); acc.y += w * bf2f(vv.y);
            acc.z += w * bf2f(vv.z); acc.w += w * bf2f(vv.w);
        }
        pacc.x += acc.x * wd; pacc.y += acc.y * wd;
        pacc.z += acc.z * wd; pacc.w += acc.w * wd;
        run++;
    }
    float* o = out + curg * 128 + lane * 4;
    atomicAdd(o + 0, pacc.x); atomicAdd(o + 1, pacc.y);
    atomicAdd(o + 2, pacc.z); atomicAdd(o + 3, pacc.w);
    if (lane == 0) atomicAdd(&cnt[curg], (float)run);
}

// ---------------- bf16 MFMA GEMM: C = act(A @ Bt^T + bias), BM=128, 512 thr ----------------
template<int K, int N, bool RELU, bool BIAS>
__global__ __launch_bounds__(512) void k_gemm_bf(const unsigned short* __restrict__ A,
        const unsigned short* __restrict__ Bt, const float* __restrict__ bias,
        unsigned short* __restrict__ C, int M) {
    constexpr int BM = 128;
    __shared__ unsigned short As[BM * K];   // XOR-swizzled rows
    __shared__ unsigned short Bs[N * K];

    const int tid = threadIdx.x;
    const int bm = blockIdx.x * BM;

    constexpr int AC = BM * K / 8;
    for (int c = tid; c < AC; c += 512) {
        int row = c / (K / 8);
        int kc  = (c % (K / 8)) * 8;
        uint4 v = make_uint4(0, 0, 0, 0);
        int gr = bm + row;
        if (gr < M) v = *(const uint4*)(A + (size_t)gr * K + kc);
        int byte = row * (2 * K) + ((kc * 2) ^ ((row & 7) << 4));
        *(uint4*)((char*)As + byte) = v;
    }
    constexpr int BC = N * K / 8;
    for (int c = tid; c < BC; c += 512) {
        int col = c / (K / 8);
        int kc  = (c % (K / 8)) * 8;
        uint4 v = *(const uint4*)(Bt + (size_t)col * K + kc);
        int byte = col * (2 * K) + ((kc * 2) ^ ((col & 7) << 4));
        *(uint4*)((char*)Bs + byte) = v;
    }
    __syncthreads();

    const int w  = tid >> 6;
    const int l  = tid & 63;
    const int lr = l & 15;
    const int lg = l >> 4;
    const int r0 = w * 16;

    constexpr int NT = N / 16;
    f32x4 acc[NT] = {};

    const int arow  = r0 + lr;
    const int abase = arow * (2 * K);
    const int aswz  = (arow & 7) << 4;

#pragma unroll
    for (int ks = 0; ks < K / 32; ++ks) {
        int kb = ks * 64 + lg * 16;
        short8 a = *(const short8*)((const char*)As + abase + (kb ^ aswz));
#pragma unroll
        for (int n = 0; n < NT; ++n) {
            int col = n * 16 + lr;
            short8 b = *(const short8*)((const char*)Bs + col * (2 * K) + (kb ^ ((col & 7) << 4)));
            acc[n] = __builtin_amdgcn_mfma_f32_16x16x32_bf16(a, b, acc[n], 0, 0, 0);
        }
    }

#pragma unroll
    for (int n = 0; n < NT; ++n) {
        int col = n * 16 + lr;
        float bb = BIAS ? bias[col] : 0.0f;
#pragma unroll
        for (int r = 0; r < 4; ++r) {
            int row = bm + r0 + lg * 4 + r;
            if (row < M) {
                float v = acc[n][r] + bb;
                if (RELU) v = fmaxf(v, 0.f);
                C[(size_t)row * N + col] = f2bf(v);
            }
        }
    }
}

__global__ void k_biasfix(const float* __restrict__ bias, const float* __restrict__ cnt,
                          float* __restrict__ out) {
    int idx = blockIdx.x * blockDim.x + threadIdx.x;
    if (idx >= NG * 128) return;
    int g = idx >> 7, c = idx & 127;
    out[idx] += bias[c] * cnt[g];
}

// ---------------- launch ----------------

extern "C" void kernel_launch(void* const* d_in, const int* in_sizes, int n_in,
                              void* d_out, int out_size, void* d_ws, size_t ws_size,
                              hipStream_t stream) {
    const float* x     = (const float*)d_in[0];
    const int*   ei    = (const int*)d_in[1];
    const int*   batch = (const int*)d_in[2];
    const float* W1    = (const float*)d_in[3];
    const float* b1    = (const float*)d_in[4];
    const float* W2    = (const float*)d_in[5];
    const float* b2    = (const float*)d_in[6];
    float* out = (float*)d_out;

    const int* src = ei;
    const int* dst = ei + NE;

    char* ws = (char*)d_ws;
    float*          dinv   = (float*)(ws + 0);
    int*            cnt_in = (int*)(ws + 524288);
    int*            rowst  = (int*)(ws + 1048576);
    int*            bsum   = (int*)(ws + 1572864);
    float*          cnt    = (float*)(ws + 1576960);
    unsigned short* w1t    = (unsigned short*)(ws + 1581056);   // 256x128 bf16
    unsigned short* w2t    = (unsigned short*)(ws + 1646592);   // 128x256 bf16
    int*            csr    = (int*)(ws + 1712128);              // 6.4 MB
    unsigned short* xbf    = (unsigned short*)(ws + 8388608);   // 25.6 MB
    unsigned short* agg1   = (unsigned short*)(ws + 33988608);  // 25.6 MB
    unsigned short* h1     = (unsigned short*)(ws + 59588608);  // 51.2 MB
    unsigned short* tbf    = (unsigned short*)(ws + 110788608); // 25.6 MB

    const int BLK = 256;
    auto cdiv = [](int a, int b) { return (a + b - 1) / b; };
    const int NB = cdiv(NN, 256);

    // ---- conversions ----
    k_cvt_bf<<<cdiv(NN * 32, BLK), BLK, 0, stream>>>(x, xbf, NN * 32);
    k_wt<<<cdiv(DI * DH, BLK), BLK, 0, stream>>>(W1, w1t, DI, DH);
    k_wt<<<cdiv(DH * DO, BLK), BLK, 0, stream>>>(W2, w2t, DH, DO);

    // ---- degree + CSR build ----
    k_zero_int<<<cdiv(NN, BLK), BLK, 0, stream>>>(cnt_in, NN);
    k_hist<<<cdiv(NE, BLK), BLK, 0, stream>>>(dst, cnt_in, NE);
    k_scan1<<<NB, 256, 0, stream>>>(cnt_in, rowst, bsum, NN);
    k_scan2<<<1, 512, 0, stream>>>(bsum, NB);
    k_scan3<<<NB, 256, 0, stream>>>(rowst, bsum, cnt_in, dinv, NN, NE);
    {
        const int NPASS = 4, NPP = (NN + NPASS - 1) / NPASS;
        for (int p = 0; p < NPASS; ++p)
            k_fill_csr<<<cdiv(NE, BLK), BLK, 0, stream>>>(src, dst, cnt_in, csr, NE,
                                                          p * NPP, (p + 1) * NPP);
    }

    // ---- layer 1 ----
    k_agg16<<<cdiv(NN * 16, BLK), BLK, 0, stream>>>(xbf, csr, rowst, dinv, agg1, NN);
    k_gemm_bf<DI, DH, true, true><<<cdiv(NN, 128), 512, 0, stream>>>(agg1, w1t, b1, h1, NN);

    // ---- layer 2 ----
    k_gemm_bf<DH, DO, false, false><<<cdiv(NN, 128), 512, 0, stream>>>(h1, w2t, nullptr, tbf, NN);

    // ---- fused agg2 + pool ----
    k_zero<<<cdiv(NG * 128, BLK), BLK, 0, stream>>>(out, NG * 128);
    k_zero<<<1, 64, 0, stream>>>(cnt, NG);
    {
        const int R = 8;
        int groups = cdiv(NN, R);
        k_agg_pool<<<cdiv(groups, 8), 256, 0, stream>>>(tbf, csr, rowst, dinv, batch, out, cnt, NN);
    }
    k_biasfix<<<cdiv(NG * 128, BLK), BLK, 0, stream>>>(b2, cnt, out);
}